// Round 1
// baseline (11598.798 us; speedup 1.0000x reference)
//
#include <hip/hip_runtime.h>
#include <hip/hip_fp16.h>
#include <cstdint>
#include <cstddef>

#define EPS_BN 1e-5f

static inline int cdiv(int a, int b) { return (a + b - 1) / b; }

__device__ __forceinline__ float atomAddF(float* p, float v) {
    return unsafeAtomicAdd(p, v);   // HW global_atomic_add_f32 on gfx950
}

// ---------------- degree / dinv ----------------
__global__ __launch_bounds__(256) void k_deg(const int* __restrict__ dst, int E,
                                             int* __restrict__ deg) {
    int e = blockIdx.x * 256 + threadIdx.x;
    if (e < E) atomicAdd(&deg[dst[e]], 1);
}

__global__ __launch_bounds__(256) void k_dinv(const int* __restrict__ deg,
                                              float* __restrict__ dinv, int n) {
    int v = blockIdx.x * 256 + threadIdx.x;
    if (v < n) dinv[v] = rsqrtf((float)(deg[v] + 1));  // +1 self loop
}

// ---------------- S = P * dinv^2 (self-loop term, also zero-init replacement) ----
template<int D>
__global__ __launch_bounds__(256) void k_self_init(const float* __restrict__ P,
                                                   const float* __restrict__ dinv,
                                                   float* __restrict__ S, int n) {
    int idx = blockIdx.x * 256 + threadIdx.x;   // float4 index
    int total = n * (D / 4);
    if (idx >= total) return;
    int r = idx / (D / 4);
    float d = dinv[r]; d *= d;
    float4 v = ((const float4*)P)[idx];
    v.x *= d; v.y *= d; v.z *= d; v.w *= d;
    ((float4*)S)[idx] = v;
}

// ---------------- edge scatter: S[dst] += P[src] * dinv[src]*dinv[dst] ----------
template<int D>
__global__ __launch_bounds__(256) void k_scatter(const int* __restrict__ src,
                                                 const int* __restrict__ dst, int E,
                                                 const float* __restrict__ P,
                                                 const float* __restrict__ dinv,
                                                 float* __restrict__ S) {
    constexpr int TPE = D / 4;        // threads per edge (float4 each)
    constexpr int EPB = 256 / TPE;    // edges per block
    int t = threadIdx.x;
    int e = blockIdx.x * EPB + t / TPE;
    if (e >= E) return;
    int c4 = t % TPE;
    int s = src[e], d = dst[e];
    float nrm = dinv[s] * dinv[d];
    float4 v = *((const float4*)(P + (size_t)s * D) + c4);
    float* o = S + (size_t)d * D + (size_t)c4 * 4;
    atomAddF(o + 0, v.x * nrm);
    atomAddF(o + 1, v.y * nrm);
    atomAddF(o + 2, v.z * nrm);
    atomAddF(o + 3, v.w * nrm);
}

// ---------------- fp32 -> fp16 conversion ----------------
__global__ __launch_bounds__(256) void k_f32_to_f16(const float* __restrict__ in,
                                                    __half* __restrict__ out, int total4) {
    int idx = blockIdx.x * 256 + threadIdx.x;
    if (idx >= total4) return;
    float4 v = ((const float4*)in)[idx];
    __half2* o = (__half2*)out + (size_t)idx * 2;
    o[0] = __floats2half2_rn(v.x, v.y);
    o[1] = __floats2half2_rn(v.z, v.w);
}

// ---------------- GEMM: C[Mpad x NC] = A(f16)[Mpad x K] @ W(f32)[K x NC] --------
template<int K, int NC>
__global__ __launch_bounds__(256) void k_gemm(const __half* __restrict__ A,
                                              const float* __restrict__ W,
                                              float* __restrict__ C) {
    __shared__ float As[64][17];
    __shared__ float Ws[16][64];
    int tid = threadIdx.x;
    int tx = tid & 15, ty = tid >> 4;
    int row0 = blockIdx.x * 64;
    int col0 = blockIdx.y * 64;
    float acc[4][4] = {};
    for (int k0 = 0; k0 < K; k0 += 16) {
        {   // A tile 64x16
            int r = tid >> 2;
            int c = (tid & 3) * 4;
            const __half* ap = A + (size_t)(row0 + r) * K + k0 + c;
            As[r][c + 0] = __half2float(ap[0]);
            As[r][c + 1] = __half2float(ap[1]);
            As[r][c + 2] = __half2float(ap[2]);
            As[r][c + 3] = __half2float(ap[3]);
        }
        {   // W tile 16x64
            int r = tid >> 4;
            int c = (tid & 15) * 4;
            float4 w = *(const float4*)(W + (size_t)(k0 + r) * NC + col0 + c);
            Ws[r][c + 0] = w.x; Ws[r][c + 1] = w.y;
            Ws[r][c + 2] = w.z; Ws[r][c + 3] = w.w;
        }
        __syncthreads();
#pragma unroll
        for (int kk = 0; kk < 16; ++kk) {
            float a0 = As[ty * 4 + 0][kk], a1 = As[ty * 4 + 1][kk];
            float a2 = As[ty * 4 + 2][kk], a3 = As[ty * 4 + 3][kk];
            float w0 = Ws[kk][tx * 4 + 0], w1 = Ws[kk][tx * 4 + 1];
            float w2 = Ws[kk][tx * 4 + 2], w3 = Ws[kk][tx * 4 + 3];
            acc[0][0] += a0 * w0; acc[0][1] += a0 * w1; acc[0][2] += a0 * w2; acc[0][3] += a0 * w3;
            acc[1][0] += a1 * w0; acc[1][1] += a1 * w1; acc[1][2] += a1 * w2; acc[1][3] += a1 * w3;
            acc[2][0] += a2 * w0; acc[2][1] += a2 * w1; acc[2][2] += a2 * w2; acc[2][3] += a2 * w3;
            acc[3][0] += a3 * w0; acc[3][1] += a3 * w1; acc[3][2] += a3 * w2; acc[3][3] += a3 * w3;
        }
        __syncthreads();
    }
#pragma unroll
    for (int i = 0; i < 4; ++i) {
        float4 st = make_float4(acc[i][0], acc[i][1], acc[i][2], acc[i][3]);
        *(float4*)(C + (size_t)(row0 + ty * 4 + i) * NC + col0 + tx * 4) = st;
    }
}

// ---------------- BatchNorm ----------------
template<int D>
__global__ __launch_bounds__(256) void k_bn_stats(const float* __restrict__ X, int n,
                                                  float* __restrict__ sums,
                                                  float* __restrict__ sqs) {
    constexpr int SUB = 256 / D;   // 1 (D=256) or 2 (D=128)
    int c = threadIdx.x % D;
    int sub = threadIdx.x / D;
    int base = blockIdx.x * 256;
    float s = 0.f, s2 = 0.f;
    for (int i = sub; i < 256; i += SUB) {
        int r = base + i;
        if (r < n) {
            float v = X[(size_t)r * D + c];
            s += v; s2 += v * v;
        }
    }
    atomAddF(&sums[c], s);
    atomAddF(&sqs[c], s2);
}

template<int D>
__global__ __launch_bounds__(256) void k_bn_fin(const float* __restrict__ sums,
                                                const float* __restrict__ sqs,
                                                const float* __restrict__ g,
                                                const float* __restrict__ beta, int n,
                                                float* __restrict__ scale,
                                                float* __restrict__ shift) {
    int c = threadIdx.x;
    if (c < D) {
        float mu = sums[c] / (float)n;
        float var = sqs[c] / (float)n - mu * mu;   // biased, matches x.var(0)
        float sc = g[c] * rsqrtf(var + EPS_BN);
        scale[c] = sc;
        shift[c] = beta[c] - mu * sc;
    }
}

template<int D>
__global__ __launch_bounds__(256) void k_bn_apply(const float* __restrict__ X,
                                                  const float* __restrict__ scale,
                                                  const float* __restrict__ shift,
                                                  __half* __restrict__ H, int n) {
    int idx = blockIdx.x * 256 + threadIdx.x;   // float4 index
    int total = n * (D / 4);
    if (idx >= total) return;
    int c = (idx % (D / 4)) * 4;
    float4 v = ((const float4*)X)[idx];
    float y0 = fmaxf(0.f, v.x * scale[c + 0] + shift[c + 0]);
    float y1 = fmaxf(0.f, v.y * scale[c + 1] + shift[c + 1]);
    float y2 = fmaxf(0.f, v.z * scale[c + 2] + shift[c + 2]);
    float y3 = fmaxf(0.f, v.w * scale[c + 3] + shift[c + 3]);
    __half2* o = (__half2*)H + (size_t)idx * 2;
    o[0] = __floats2half2_rn(y0, y1);
    o[1] = __floats2half2_rn(y2, y3);
}

// ---------------- final: out = H3(f16)[n x 128] @ Wout[128 x 10] + bout --------
__global__ __launch_bounds__(256) void k_out(const __half* __restrict__ H,
                                             const float* __restrict__ Wout,
                                             const float* __restrict__ bout,
                                             float* __restrict__ out, int n) {
    __shared__ float Wl[128 * 10];
    __shared__ float bl[10];
    __shared__ float red[64 * 40];
    int tid = threadIdx.x;
    for (int i = tid; i < 1280; i += 256) Wl[i] = Wout[i];
    if (tid < 10) bl[tid] = bout[tid];
    __syncthreads();
    int rl = tid >> 2;      // 0..63
    int q = tid & 3;        // quarter of the row
    int r = blockIdx.x * 64 + rl;
    float p[10] = {};
    if (r < n) {
        const __half* a = H + (size_t)r * 128 + q * 32;
#pragma unroll 8
        for (int k = 0; k < 32; ++k) {
            float av = __half2float(a[k]);
            const float* wr = Wl + (q * 32 + k) * 10;
#pragma unroll
            for (int c = 0; c < 10; ++c) p[c] += av * wr[c];
        }
    }
    float* rr = red + (size_t)(rl * 4 + q) * 10;
#pragma unroll
    for (int c = 0; c < 10; ++c) rr[c] = p[c];
    __syncthreads();
    if (q == 0 && r < n) {
        const float* rb = red + (size_t)rl * 40;
#pragma unroll
        for (int c = 0; c < 10; ++c) {
            out[(size_t)r * 10 + c] = rb[c] + rb[10 + c] + rb[20 + c] + rb[30 + c] + bl[c];
        }
    }
}

// ---------------- launch ----------------
extern "C" void kernel_launch(void* const* d_in, const int* in_sizes, int n_in,
                              void* d_out, int out_size, void* d_ws, size_t ws_size,
                              hipStream_t stream) {
    const float* x    = (const float*)d_in[0];
    const int*   ei   = (const int*)d_in[1];
    const float* W1   = (const float*)d_in[2];
    const float* g1   = (const float*)d_in[4];
    const float* be1  = (const float*)d_in[5];
    const float* W2   = (const float*)d_in[6];
    const float* g2   = (const float*)d_in[8];
    const float* be2  = (const float*)d_in[9];
    const float* W3   = (const float*)d_in[10];
    const float* g3   = (const float*)d_in[12];
    const float* be3  = (const float*)d_in[13];
    const float* Wout = (const float*)d_in[14];
    const float* bout = (const float*)d_in[15];
    float* out = (float*)d_out;

    int n = in_sizes[0] / 128;
    int E = in_sizes[1] / 2;
    const int* esrc = ei;
    const int* edst = ei + E;
    int npad = cdiv(n, 128) * 128;

    char* ws = (char*)d_ws;
    size_t align = 256;
    size_t o_deg   = 0;
    size_t sz_n4   = (((size_t)n * 4) + align - 1) & ~(align - 1);
    size_t o_dinv  = o_deg + sz_n4;
    size_t o_stats = o_dinv + sz_n4;
    size_t o_R1    = o_stats + 4096;
    size_t szR     = (size_t)npad * 256 * 4;
    size_t o_R2    = o_R1 + szR;
    size_t o_R3    = o_R2 + szR;
    size_t need    = o_R3 + (size_t)npad * 256 * 2;
    if (ws_size < need) return;  // workspace too small -> fail validation loudly

    int*   deg   = (int*)(ws + o_deg);
    float* dinv  = (float*)(ws + o_dinv);
    float* sums  = (float*)(ws + o_stats);
    float* sqs   = (float*)(ws + o_stats + 1024);
    float* scale = (float*)(ws + o_stats + 2048);
    float* shift = (float*)(ws + o_stats + 3072);
    float* R1f   = (float*)(ws + o_R1);
    float* R2f   = (float*)(ws + o_R2);
    __half* R3h  = (__half*)(ws + o_R3);

    // degree + dinv
    hipMemsetAsync(deg, 0, (size_t)n * 4, stream);
    k_deg<<<cdiv(E, 256), 256, 0, stream>>>(edst, E, deg);
    k_dinv<<<cdiv(n, 256), 256, 0, stream>>>(deg, dinv, n);

    // ---- layer 1: S0 = A_hat x ; P1 = S0 @ W1 ; BN+ReLU -> H1 ----
    k_self_init<128><<<cdiv(n * 32, 256), 256, 0, stream>>>(x, dinv, R1f, n);
    k_scatter<128><<<cdiv(E, 8), 256, 0, stream>>>(esrc, edst, E, x, dinv, R1f);
    k_f32_to_f16<<<cdiv(n * 32, 256), 256, 0, stream>>>(R1f, R3h, n * 32);
    k_gemm<128, 256><<<dim3(npad / 64, 4), 256, 0, stream>>>(R3h, W1, R2f);
    hipMemsetAsync(sums, 0, 2048, stream);
    k_bn_stats<256><<<cdiv(n, 256), 256, 0, stream>>>(R2f, n, sums, sqs);
    k_bn_fin<256><<<1, 256, 0, stream>>>(sums, sqs, g1, be1, n, scale, shift);
    k_bn_apply<256><<<cdiv(n * 64, 256), 256, 0, stream>>>(R2f, scale, shift, R3h, n);

    // ---- layer 2: P2 = H1 @ W2 ; S2 = A_hat P2 ; BN+ReLU -> H2 ----
    k_gemm<256, 256><<<dim3(npad / 64, 4), 256, 0, stream>>>(R3h, W2, R1f);
    k_self_init<256><<<cdiv(n * 64, 256), 256, 0, stream>>>(R1f, dinv, R2f, n);
    k_scatter<256><<<cdiv(E, 4), 256, 0, stream>>>(esrc, edst, E, R1f, dinv, R2f);
    hipMemsetAsync(sums, 0, 2048, stream);
    k_bn_stats<256><<<cdiv(n, 256), 256, 0, stream>>>(R2f, n, sums, sqs);
    k_bn_fin<256><<<1, 256, 0, stream>>>(sums, sqs, g2, be2, n, scale, shift);
    k_bn_apply<256><<<cdiv(n * 64, 256), 256, 0, stream>>>(R2f, scale, shift, R3h, n);

    // ---- layer 3: P3 = H2 @ W3 ; S3 = A_hat P3 ; BN+ReLU -> H3 ----
    k_gemm<256, 128><<<dim3(npad / 64, 2), 256, 0, stream>>>(R3h, W3, R1f);
    k_self_init<128><<<cdiv(n * 32, 256), 256, 0, stream>>>(R1f, dinv, R2f, n);
    k_scatter<128><<<cdiv(E, 8), 256, 0, stream>>>(esrc, edst, E, R1f, dinv, R2f);
    hipMemsetAsync(sums, 0, 2048, stream);
    k_bn_stats<128><<<cdiv(n, 256), 256, 0, stream>>>(R2f, n, sums, sqs);
    k_bn_fin<128><<<1, 128, 0, stream>>>(sums, sqs, g3, be3, n, scale, shift);
    k_bn_apply<128><<<cdiv(n * 32, 256), 256, 0, stream>>>(R2f, scale, shift, R3h, n);

    // ---- output layer ----
    k_out<<<cdiv(n, 64), 256, 0, stream>>>(R3h, Wout, bout, out, n);
}

// Round 2
// 1460.439 us; speedup vs baseline: 7.9420x; 7.9420x over previous
//
#include <hip/hip_runtime.h>
#include <hip/hip_fp16.h>
#include <cstdint>
#include <cstddef>
#include <type_traits>

#define EPS_BN 1e-5f

static inline int cdiv(int a, int b) { return (a + b - 1) / b; }

__device__ __forceinline__ float atomAddF(float* p, float v) {
    return unsafeAtomicAdd(p, v);   // HW global_atomic_add_f32 on gfx950
}

// ---------------- degree count ----------------
__global__ __launch_bounds__(256) void k_deg(const int* __restrict__ dst, int E,
                                             int* __restrict__ deg) {
    int e = blockIdx.x * 256 + threadIdx.x;
    if (e < E) atomicAdd(&deg[dst[e]], 1);
}

// dinv = rsqrt(deg+1), written IN PLACE over deg (runs after the scan reads deg)
__global__ __launch_bounds__(256) void k_dinv(int* __restrict__ degdinv, int n) {
    int v = blockIdx.x * 256 + threadIdx.x;
    if (v < n) {
        float d = (float)(degdinv[v] + 1);
        ((float*)degdinv)[v] = rsqrtf(d);
    }
}

// ---------------- exclusive scan of deg -> off (1024 elems / block) ----------------
__global__ __launch_bounds__(256) void k_scan_reduce(const int* __restrict__ deg, int n,
                                                     int* __restrict__ bsum) {
    int base = blockIdx.x * 1024;
    int t = threadIdx.x;
    int s = 0;
#pragma unroll
    for (int i = 0; i < 4; ++i) {
        int idx = base + t * 4 + i;
        if (idx < n) s += deg[idx];
    }
    __shared__ int sm[256];
    sm[t] = s;
    __syncthreads();
    for (int off = 128; off > 0; off >>= 1) {
        if (t < off) sm[t] += sm[t + off];
        __syncthreads();
    }
    if (t == 0) bsum[blockIdx.x] = sm[0];
}

__global__ void k_scan_bsum(int* __restrict__ bsum, int nb) {
    if (threadIdx.x == 0 && blockIdx.x == 0) {
        int acc = 0;
        for (int i = 0; i < nb; ++i) { int v = bsum[i]; bsum[i] = acc; acc += v; }
    }
}

__global__ __launch_bounds__(256) void k_scan_final(const int* __restrict__ deg, int n,
                                                    const int* __restrict__ bsum,
                                                    int* __restrict__ off_) {
    int base = blockIdx.x * 1024;
    int t = threadIdx.x;
    int v[4];
    int s = 0;
#pragma unroll
    for (int i = 0; i < 4; ++i) {
        int idx = base + t * 4 + i;
        v[i] = (idx < n) ? deg[idx] : 0;
        s += v[i];
    }
    __shared__ int sm[256];
    sm[t] = s;
    __syncthreads();
    for (int off = 1; off < 256; off <<= 1) {        // Hillis-Steele inclusive
        int x = (t >= off) ? sm[t - off] : 0;
        __syncthreads();
        sm[t] += x;
        __syncthreads();
    }
    int excl = sm[t] - s + bsum[blockIdx.x];
#pragma unroll
    for (int i = 0; i < 4; ++i) {
        int idx = base + t * 4 + i;
        if (idx < n) { off_[idx] = excl; excl += v[i]; }
    }
}

// fill, using off as atomic cursors. After this, off[v] == row-end of v,
// row-begin of v == (v ? off[v-1] : 0).
__global__ __launch_bounds__(256) void k_fill(const int* __restrict__ src,
                                              const int* __restrict__ dst, int E,
                                              int* __restrict__ off_,
                                              int* __restrict__ csr) {
    int e = blockIdx.x * 256 + threadIdx.x;
    if (e < E) {
        int d = dst[e];
        int p = atomicAdd(&off_[d], 1);
        csr[p] = src[e];
    }
}

// ---------------- CSR gather: S[v] = sum_{s in N(v)} P[s]*dinv[s]*dinv[v] + P[v]*dinv[v]^2
template<int D, typename OT>
__global__ __launch_bounds__(256) void k_gather(const int* __restrict__ csr,
                                                const int* __restrict__ endoff,
                                                const float* __restrict__ P,
                                                const float* __restrict__ dinv,
                                                OT* __restrict__ S, int n) {
    constexpr int LPN = D / 4;          // lanes per node (float4 each)
    constexpr int NPB = 256 / LPN;      // nodes per block
    int v = blockIdx.x * NPB + threadIdx.x / LPN;
    if (v >= n) return;
    int lane = threadIdx.x % LPN;
    int beg = (v == 0) ? 0 : endoff[v - 1];
    int end = endoff[v];
    float dv = dinv[v];
    float dd = dv * dv;
    float4 acc = ((const float4*)(P + (size_t)v * D))[lane];
    acc.x *= dd; acc.y *= dd; acc.z *= dd; acc.w *= dd;
    int i = beg;
    for (; i + 1 < end; i += 2) {       // 2-wide: two independent loads in flight
        int s0 = csr[i], s1 = csr[i + 1];
        float w0 = dinv[s0] * dv, w1 = dinv[s1] * dv;
        float4 p0 = ((const float4*)(P + (size_t)s0 * D))[lane];
        float4 p1 = ((const float4*)(P + (size_t)s1 * D))[lane];
        acc.x += p0.x * w0 + p1.x * w1;
        acc.y += p0.y * w0 + p1.y * w1;
        acc.z += p0.z * w0 + p1.z * w1;
        acc.w += p0.w * w0 + p1.w * w1;
    }
    if (i < end) {
        int s0 = csr[i];
        float w0 = dinv[s0] * dv;
        float4 p0 = ((const float4*)(P + (size_t)s0 * D))[lane];
        acc.x += p0.x * w0; acc.y += p0.y * w0;
        acc.z += p0.z * w0; acc.w += p0.w * w0;
    }
    if constexpr (std::is_same<OT, float>::value) {
        ((float4*)(S + (size_t)v * D))[lane] = acc;
    } else {
        __half2* o = (__half2*)(S + (size_t)v * D) + (size_t)lane * 2;
        o[0] = __floats2half2_rn(acc.x, acc.y);
        o[1] = __floats2half2_rn(acc.z, acc.w);
    }
}

// ---------------- GEMM: C[Mpad x NC] = A(f16)[Mpad x K] @ W(f32)[K x NC] --------
template<int K, int NC>
__global__ __launch_bounds__(256) void k_gemm(const __half* __restrict__ A,
                                              const float* __restrict__ W,
                                              float* __restrict__ C) {
    __shared__ float As[64][17];
    __shared__ float Ws[16][64];
    int tid = threadIdx.x;
    int tx = tid & 15, ty = tid >> 4;
    int row0 = blockIdx.x * 64;
    int col0 = blockIdx.y * 64;
    float acc[4][4] = {};
    for (int k0 = 0; k0 < K; k0 += 16) {
        {   // A tile 64x16
            int r = tid >> 2;
            int c = (tid & 3) * 4;
            const __half* ap = A + (size_t)(row0 + r) * K + k0 + c;
            As[r][c + 0] = __half2float(ap[0]);
            As[r][c + 1] = __half2float(ap[1]);
            As[r][c + 2] = __half2float(ap[2]);
            As[r][c + 3] = __half2float(ap[3]);
        }
        {   // W tile 16x64
            int r = tid >> 4;
            int c = (tid & 15) * 4;
            float4 w = *(const float4*)(W + (size_t)(k0 + r) * NC + col0 + c);
            Ws[r][c + 0] = w.x; Ws[r][c + 1] = w.y;
            Ws[r][c + 2] = w.z; Ws[r][c + 3] = w.w;
        }
        __syncthreads();
#pragma unroll
        for (int kk = 0; kk < 16; ++kk) {
            float a0 = As[ty * 4 + 0][kk], a1 = As[ty * 4 + 1][kk];
            float a2 = As[ty * 4 + 2][kk], a3 = As[ty * 4 + 3][kk];
            float w0 = Ws[kk][tx * 4 + 0], w1 = Ws[kk][tx * 4 + 1];
            float w2 = Ws[kk][tx * 4 + 2], w3 = Ws[kk][tx * 4 + 3];
            acc[0][0] += a0 * w0; acc[0][1] += a0 * w1; acc[0][2] += a0 * w2; acc[0][3] += a0 * w3;
            acc[1][0] += a1 * w0; acc[1][1] += a1 * w1; acc[1][2] += a1 * w2; acc[1][3] += a1 * w3;
            acc[2][0] += a2 * w0; acc[2][1] += a2 * w1; acc[2][2] += a2 * w2; acc[2][3] += a2 * w3;
            acc[3][0] += a3 * w0; acc[3][1] += a3 * w1; acc[3][2] += a3 * w2; acc[3][3] += a3 * w3;
        }
        __syncthreads();
    }
#pragma unroll
    for (int i = 0; i < 4; ++i) {
        float4 st = make_float4(acc[i][0], acc[i][1], acc[i][2], acc[i][3]);
        *(float4*)(C + (size_t)(row0 + ty * 4 + i) * NC + col0 + tx * 4) = st;
    }
}

// ---------------- BatchNorm ----------------
template<int D>
__global__ __launch_bounds__(256) void k_bn_stats(const float* __restrict__ X, int n,
                                                  float* __restrict__ sums,
                                                  float* __restrict__ sqs) {
    constexpr int SUB = 256 / D;
    int c = threadIdx.x % D;
    int sub = threadIdx.x / D;
    int base = blockIdx.x * 256;
    float s = 0.f, s2 = 0.f;
    for (int i = sub; i < 256; i += SUB) {
        int r = base + i;
        if (r < n) {
            float v = X[(size_t)r * D + c];
            s += v; s2 += v * v;
        }
    }
    atomAddF(&sums[c], s);
    atomAddF(&sqs[c], s2);
}

template<int D>
__global__ __launch_bounds__(256) void k_bn_fin(const float* __restrict__ sums,
                                                const float* __restrict__ sqs,
                                                const float* __restrict__ g,
                                                const float* __restrict__ beta, int n,
                                                float* __restrict__ scale,
                                                float* __restrict__ shift) {
    int c = threadIdx.x;
    if (c < D) {
        float mu = sums[c] / (float)n;
        float var = sqs[c] / (float)n - mu * mu;
        float sc = g[c] * rsqrtf(var + EPS_BN);
        scale[c] = sc;
        shift[c] = beta[c] - mu * sc;
    }
}

template<int D>
__global__ __launch_bounds__(256) void k_bn_apply(const float* __restrict__ X,
                                                  const float* __restrict__ scale,
                                                  const float* __restrict__ shift,
                                                  __half* __restrict__ H, int n) {
    int idx = blockIdx.x * 256 + threadIdx.x;
    int total = n * (D / 4);
    if (idx >= total) return;
    int c = (idx % (D / 4)) * 4;
    float4 v = ((const float4*)X)[idx];
    float y0 = fmaxf(0.f, v.x * scale[c + 0] + shift[c + 0]);
    float y1 = fmaxf(0.f, v.y * scale[c + 1] + shift[c + 1]);
    float y2 = fmaxf(0.f, v.z * scale[c + 2] + shift[c + 2]);
    float y3 = fmaxf(0.f, v.w * scale[c + 3] + shift[c + 3]);
    __half2* o = (__half2*)H + (size_t)idx * 2;
    o[0] = __floats2half2_rn(y0, y1);
    o[1] = __floats2half2_rn(y2, y3);
}

// ---------------- final linear ----------------
__global__ __launch_bounds__(256) void k_out(const __half* __restrict__ H,
                                             const float* __restrict__ Wout,
                                             const float* __restrict__ bout,
                                             float* __restrict__ out, int n) {
    __shared__ float Wl[128 * 10];
    __shared__ float bl[10];
    __shared__ float red[64 * 40];
    int tid = threadIdx.x;
    for (int i = tid; i < 1280; i += 256) Wl[i] = Wout[i];
    if (tid < 10) bl[tid] = bout[tid];
    __syncthreads();
    int rl = tid >> 2;
    int q = tid & 3;
    int r = blockIdx.x * 64 + rl;
    float p[10] = {};
    if (r < n) {
        const __half* a = H + (size_t)r * 128 + q * 32;
#pragma unroll 8
        for (int k = 0; k < 32; ++k) {
            float av = __half2float(a[k]);
            const float* wr = Wl + (q * 32 + k) * 10;
#pragma unroll
            for (int c = 0; c < 10; ++c) p[c] += av * wr[c];
        }
    }
    float* rr = red + (size_t)(rl * 4 + q) * 10;
#pragma unroll
    for (int c = 0; c < 10; ++c) rr[c] = p[c];
    __syncthreads();
    if (q == 0 && r < n) {
        const float* rb = red + (size_t)rl * 40;
#pragma unroll
        for (int c = 0; c < 10; ++c) {
            out[(size_t)r * 10 + c] = rb[c] + rb[10 + c] + rb[20 + c] + rb[30 + c] + bl[c];
        }
    }
}

// ---------------- launch ----------------
extern "C" void kernel_launch(void* const* d_in, const int* in_sizes, int n_in,
                              void* d_out, int out_size, void* d_ws, size_t ws_size,
                              hipStream_t stream) {
    const float* x    = (const float*)d_in[0];
    const int*   ei   = (const int*)d_in[1];
    const float* W1   = (const float*)d_in[2];
    const float* g1   = (const float*)d_in[4];
    const float* be1  = (const float*)d_in[5];
    const float* W2   = (const float*)d_in[6];
    const float* g2   = (const float*)d_in[8];
    const float* be2  = (const float*)d_in[9];
    const float* W3   = (const float*)d_in[10];
    const float* g3   = (const float*)d_in[12];
    const float* be3  = (const float*)d_in[13];
    const float* Wout = (const float*)d_in[14];
    const float* bout = (const float*)d_in[15];
    float* out = (float*)d_out;

    int n = in_sizes[0] / 128;
    int E = in_sizes[1] / 2;
    const int* esrc = ei;
    const int* edst = ei + E;
    int npad = cdiv(n, 64) * 64;
    int nb = cdiv(n, 1024);

    const size_t align = 256;
    auto al = [&](size_t s) { return (s + align - 1) & ~(align - 1); };
    size_t n4 = al((size_t)n * 4);
    size_t E4 = al((size_t)E * 4);
    size_t szR = (size_t)npad * 256 * 4;

    char* ws = (char*)d_ws;
    size_t o_deg   = 0;               // deg, then dinv in-place (n * 4B)
    size_t o_off   = o_deg + n4;      // CSR row ends (n * 4B)
    size_t o_csr   = o_off + n4;      // CSR src indices (E * 4B)
    size_t o_stats = o_csr + E4;      // sums/sqs/scale/shift + bsum (8 KB)
    size_t o_R1    = o_stats + 8192;
    size_t o_R2    = o_R1 + szR;
    size_t o_R3    = o_R2 + szR;
    size_t need    = o_R3 + (size_t)npad * 256 * 2;
    if (ws_size < need) return;

    int*   deg   = (int*)(ws + o_deg);
    float* dinv  = (float*)(ws + o_deg);     // in-place after scan
    int*   off_  = (int*)(ws + o_off);
    int*   csr   = (int*)(ws + o_csr);
    float* sums  = (float*)(ws + o_stats);
    float* sqs   = (float*)(ws + o_stats + 1024);
    float* scale = (float*)(ws + o_stats + 2048);
    float* shift = (float*)(ws + o_stats + 3072);
    int*   bsum  = (int*)(ws + o_stats + 4096);
    float* R1f   = (float*)(ws + o_R1);
    float* R2f   = (float*)(ws + o_R2);
    __half* R3h  = (__half*)(ws + o_R3);

    // ---- CSR build ----
    hipMemsetAsync(deg, 0, (size_t)n * 4, stream);
    k_deg<<<cdiv(E, 256), 256, 0, stream>>>(edst, E, deg);
    k_scan_reduce<<<nb, 256, 0, stream>>>(deg, n, bsum);
    k_scan_bsum<<<1, 64, 0, stream>>>(bsum, nb);
    k_scan_final<<<nb, 256, 0, stream>>>(deg, n, bsum, off_);
    k_dinv<<<cdiv(n, 256), 256, 0, stream>>>(deg, n);           // deg -> dinv in place
    k_fill<<<cdiv(E, 256), 256, 0, stream>>>(esrc, edst, E, off_, csr);

    // ---- layer 1: S0 = A_hat x (f16 out) ; P1 = S0 @ W1 ; BN+ReLU -> H1 ----
    k_gather<128, __half><<<cdiv(n, 8), 256, 0, stream>>>(csr, off_, x, dinv, R3h, n);
    k_gemm<128, 256><<<dim3(npad / 64, 4), 256, 0, stream>>>(R3h, W1, R2f);
    hipMemsetAsync(sums, 0, 2048, stream);
    k_bn_stats<256><<<cdiv(n, 256), 256, 0, stream>>>(R2f, n, sums, sqs);
    k_bn_fin<256><<<1, 256, 0, stream>>>(sums, sqs, g1, be1, n, scale, shift);
    k_bn_apply<256><<<cdiv(n * 64, 256), 256, 0, stream>>>(R2f, scale, shift, R3h, n);

    // ---- layer 2: P2 = H1 @ W2 ; S2 = A_hat P2 ; BN+ReLU -> H2 ----
    k_gemm<256, 256><<<dim3(npad / 64, 4), 256, 0, stream>>>(R3h, W2, R1f);
    k_gather<256, float><<<cdiv(n, 4), 256, 0, stream>>>(csr, off_, R1f, dinv, R2f, n);
    hipMemsetAsync(sums, 0, 2048, stream);
    k_bn_stats<256><<<cdiv(n, 256), 256, 0, stream>>>(R2f, n, sums, sqs);
    k_bn_fin<256><<<1, 256, 0, stream>>>(sums, sqs, g2, be2, n, scale, shift);
    k_bn_apply<256><<<cdiv(n * 64, 256), 256, 0, stream>>>(R2f, scale, shift, R3h, n);

    // ---- layer 3: P3 = H2 @ W3 ; S3 = A_hat P3 ; BN+ReLU -> H3 ----
    k_gemm<256, 128><<<dim3(npad / 64, 2), 256, 0, stream>>>(R3h, W3, R1f);
    k_gather<128, float><<<cdiv(n, 8), 256, 0, stream>>>(csr, off_, R1f, dinv, R2f, n);
    hipMemsetAsync(sums, 0, 2048, stream);
    k_bn_stats<128><<<cdiv(n, 256), 256, 0, stream>>>(R2f, n, sums, sqs);
    k_bn_fin<128><<<1, 128, 0, stream>>>(sums, sqs, g3, be3, n, scale, shift);
    k_bn_apply<128><<<cdiv(n * 32, 256), 256, 0, stream>>>(R2f, scale, shift, R3h, n);

    // ---- output layer ----
    k_out<<<cdiv(n, 64), 256, 0, stream>>>(R3h, Wout, bout, out, n);
}

// Round 3
// 967.538 us; speedup vs baseline: 11.9879x; 1.5094x over previous
//
#include <hip/hip_runtime.h>
#include <hip/hip_fp16.h>
#include <cstdint>
#include <cstddef>

#define EPS_BN 1e-5f

static inline int cdiv(int a, int b) { return (a + b - 1) / b; }

using half8  = __attribute__((ext_vector_type(8))) _Float16;
using floatx4 = __attribute__((ext_vector_type(4))) float;

__device__ __forceinline__ float atomAddF(float* p, float v) {
    return unsafeAtomicAdd(p, v);   // HW global_atomic_add_f32 on gfx950
}

// ---------------- degree count ----------------
__global__ __launch_bounds__(256) void k_deg(const int* __restrict__ dst, int E,
                                             int* __restrict__ deg) {
    int e = blockIdx.x * 256 + threadIdx.x;
    if (e < E) atomicAdd(&deg[dst[e]], 1);
}

// dinv = rsqrt(deg+1) IN PLACE over deg (after scan has consumed deg)
__global__ __launch_bounds__(256) void k_dinv(int* __restrict__ degdinv, int n) {
    int v = blockIdx.x * 256 + threadIdx.x;
    if (v < n) {
        float d = (float)(degdinv[v] + 1);
        ((float*)degdinv)[v] = rsqrtf(d);
    }
}

// ---------------- exclusive scan of deg -> off ----------------
__global__ __launch_bounds__(256) void k_scan_reduce(const int* __restrict__ deg, int n,
                                                     int* __restrict__ bsum) {
    int base = blockIdx.x * 1024;
    int t = threadIdx.x;
    int s = 0;
#pragma unroll
    for (int i = 0; i < 4; ++i) {
        int idx = base + t * 4 + i;
        if (idx < n) s += deg[idx];
    }
    __shared__ int sm[256];
    sm[t] = s;
    __syncthreads();
    for (int off = 128; off > 0; off >>= 1) {
        if (t < off) sm[t] += sm[t + off];
        __syncthreads();
    }
    if (t == 0) bsum[blockIdx.x] = sm[0];
}

__global__ void k_scan_bsum(int* __restrict__ bsum, int nb) {
    if (threadIdx.x == 0 && blockIdx.x == 0) {
        int acc = 0;
        for (int i = 0; i < nb; ++i) { int v = bsum[i]; bsum[i] = acc; acc += v; }
    }
}

__global__ __launch_bounds__(256) void k_scan_final(const int* __restrict__ deg, int n,
                                                    const int* __restrict__ bsum,
                                                    int* __restrict__ off_) {
    int base = blockIdx.x * 1024;
    int t = threadIdx.x;
    int v[4];
    int s = 0;
#pragma unroll
    for (int i = 0; i < 4; ++i) {
        int idx = base + t * 4 + i;
        v[i] = (idx < n) ? deg[idx] : 0;
        s += v[i];
    }
    __shared__ int sm[256];
    sm[t] = s;
    __syncthreads();
    for (int off = 1; off < 256; off <<= 1) {
        int x = (t >= off) ? sm[t - off] : 0;
        __syncthreads();
        sm[t] += x;
        __syncthreads();
    }
    int excl = sm[t] - s + bsum[blockIdx.x];
#pragma unroll
    for (int i = 0; i < 4; ++i) {
        int idx = base + t * 4 + i;
        if (idx < n) { off_[idx] = excl; excl += v[i]; }
    }
}

// fill using off as atomic cursors. After: off[v] == row end; begin = off[v-1].
__global__ __launch_bounds__(256) void k_fill(const int* __restrict__ src,
                                              const int* __restrict__ dst, int E,
                                              int* __restrict__ off_,
                                              int* __restrict__ csr) {
    int e = blockIdx.x * 256 + threadIdx.x;
    if (e < E) {
        int d = dst[e];
        int p = atomicAdd(&off_[d], 1);
        csr[p] = src[e];
    }
}

// ---------------- weight convert+transpose: W[K][NC] f32 -> Wt[NC][K] f16 ------
template<int K, int NC>
__global__ __launch_bounds__(256) void k_wt(const float* __restrict__ W,
                                            __half* __restrict__ Wt) {
    int idx = blockIdx.x * 256 + threadIdx.x;
    if (idx >= K * NC) return;
    int k = idx / NC, c = idx % NC;
    Wt[(size_t)c * K + k] = __float2half(W[idx]);
}

// ---------------- x (f32) -> xh (f16), pre-scaled by dinv[row] ----------------
__global__ __launch_bounds__(256) void k_x2h(const float* __restrict__ x,
                                             const float* __restrict__ dinv,
                                             __half* __restrict__ xh, int n) {
    int idx = blockIdx.x * 256 + threadIdx.x;   // 8-half output chunks, D=128
    int total = n * 16;
    if (idx >= total) return;
    int row = idx >> 4;
    float dv = dinv[row];
    const float4* p = (const float4*)x + (size_t)idx * 2;
    float4 a = p[0], b = p[1];
    uint4 o; __half2* oh = (__half2*)&o;
    oh[0] = __floats2half2_rn(a.x * dv, a.y * dv);
    oh[1] = __floats2half2_rn(a.z * dv, a.w * dv);
    oh[2] = __floats2half2_rn(b.x * dv, b.y * dv);
    oh[3] = __floats2half2_rn(b.z * dv, b.w * dv);
    ((uint4*)xh)[idx] = o;
}

// ---------------- CSR gather on pre-scaled rows: S[v] = dinv[v] * sum rows ------
template<int D>
__global__ __launch_bounds__(256) void k_gather_h(const int* __restrict__ csr,
                                                  const int* __restrict__ endoff,
                                                  const __half* __restrict__ P,
                                                  const float* __restrict__ dinv,
                                                  __half* __restrict__ S, int n) {
    constexpr int LPN = D / 8;          // 16 B per lane
    constexpr int NPB = 256 / LPN;
    int v = blockIdx.x * NPB + threadIdx.x / LPN;
    if (v >= n) return;
    int lane = threadIdx.x % LPN;
    int beg = (v == 0) ? 0 : endoff[v - 1];
    int end = endoff[v];
    float dv = dinv[v];
    float acc[8];
    {
        uint4 d = *((const uint4*)(P + (size_t)v * D) + lane);   // self term
        const __half2* h = (const __half2*)&d;
#pragma unroll
        for (int j = 0; j < 4; ++j) {
            float2 f = __half22float2(h[j]);
            acc[2 * j] = f.x; acc[2 * j + 1] = f.y;
        }
    }
    int i = beg;
    for (; i + 1 < end; i += 2) {
        int s0 = csr[i], s1 = csr[i + 1];
        uint4 d0 = *((const uint4*)(P + (size_t)s0 * D) + lane);
        uint4 d1 = *((const uint4*)(P + (size_t)s1 * D) + lane);
        const __half2* h0 = (const __half2*)&d0;
        const __half2* h1 = (const __half2*)&d1;
#pragma unroll
        for (int j = 0; j < 4; ++j) {
            float2 f0 = __half22float2(h0[j]);
            float2 f1 = __half22float2(h1[j]);
            acc[2 * j] += f0.x + f1.x;
            acc[2 * j + 1] += f0.y + f1.y;
        }
    }
    if (i < end) {
        int s0 = csr[i];
        uint4 d0 = *((const uint4*)(P + (size_t)s0 * D) + lane);
        const __half2* h0 = (const __half2*)&d0;
#pragma unroll
        for (int j = 0; j < 4; ++j) {
            float2 f0 = __half22float2(h0[j]);
            acc[2 * j] += f0.x; acc[2 * j + 1] += f0.y;
        }
    }
    uint4 o; __half2* oh = (__half2*)&o;
#pragma unroll
    for (int j = 0; j < 4; ++j)
        oh[j] = __floats2half2_rn(acc[2 * j] * dv, acc[2 * j + 1] * dv);
    *((uint4*)(S + (size_t)v * D) + lane) = o;
}

// ---------------- MFMA GEMM: C[npad x NC](f16) = A(f16) @ Wt(f16,NxK)^T --------
// Optionally scales output rows by dinv[row] (producer-side scaling for gather).
template<int K, int NC, bool SCALE>
__global__ __launch_bounds__(256) void k_gemm_mfma(const __half* __restrict__ A,
                                                   const __half* __restrict__ Wt,
                                                   const float* __restrict__ dinv,
                                                   __half* __restrict__ C, int n) {
    constexpr int LDA = 40;             // 32 + 8 halfs pad -> max 2-way bank alias
    __shared__ _Float16 As[128 * LDA];
    __shared__ _Float16 Bs[64 * LDA];
    int tid = threadIdx.x;
    int wave = tid >> 6, lane = tid & 63;
    int q = lane >> 4, l16 = lane & 15;
    int row0 = blockIdx.x * 128;
    int col0 = blockIdx.y * 64;
    floatx4 acc[2][4];
#pragma unroll
    for (int r = 0; r < 2; ++r)
#pragma unroll
        for (int c = 0; c < 4; ++c) acc[r][c] = (floatx4)0.0f;

    for (int k0 = 0; k0 < K; k0 += 32) {
#pragma unroll
        for (int i = 0; i < 2; ++i) {       // A tile 128 x 32
            int s = tid + i * 256;
            int r = s >> 2, ks = s & 3;
            uint4 d = *(const uint4*)(A + (size_t)(row0 + r) * K + k0 + ks * 8);
            *(uint4*)&As[r * LDA + ks * 8] = d;
        }
        {                                    // B tile 64 x 32 (Wt rows = out cols)
            int r = tid >> 2, ks = tid & 3;
            uint4 d = *(const uint4*)(Wt + (size_t)(col0 + r) * K + k0 + ks * 8);
            *(uint4*)&Bs[r * LDA + ks * 8] = d;
        }
        __syncthreads();
        half8 bf[4];
#pragma unroll
        for (int c = 0; c < 4; ++c)
            bf[c] = *(const half8*)&Bs[(c * 16 + l16) * LDA + q * 8];
#pragma unroll
        for (int r = 0; r < 2; ++r) {
            half8 af = *(const half8*)&As[(wave * 32 + r * 16 + l16) * LDA + q * 8];
#pragma unroll
            for (int c = 0; c < 4; ++c)
                acc[r][c] = __builtin_amdgcn_mfma_f32_16x16x32_f16(af, bf[c], acc[r][c], 0, 0, 0);
        }
        __syncthreads();
    }
#pragma unroll
    for (int r = 0; r < 2; ++r) {
#pragma unroll
        for (int reg = 0; reg < 4; ++reg) {
            int grow = row0 + wave * 32 + r * 16 + q * 4 + reg;
            float sc = 1.f;
            if (SCALE) sc = (grow < n) ? dinv[grow] : 0.f;
            __half* cp = C + (size_t)grow * NC + col0 + l16;
#pragma unroll
            for (int c = 0; c < 4; ++c)
                cp[c * 16] = __float2half(acc[r][c][reg] * sc);
        }
    }
}

// ---------------- BatchNorm (f16 in) ----------------
template<int D>
__global__ __launch_bounds__(256) void k_bn_stats_h(const __half* __restrict__ X, int n,
                                                    float* __restrict__ sums,
                                                    float* __restrict__ sqs) {
    constexpr int SUB = 256 / D;
    int c = threadIdx.x % D;
    int sub = threadIdx.x / D;
    int base = blockIdx.x * 256;
    float s = 0.f, s2 = 0.f;
    for (int i = sub; i < 256; i += SUB) {
        int r = base + i;
        if (r < n) {
            float v = __half2float(X[(size_t)r * D + c]);
            s += v; s2 += v * v;
        }
    }
    atomAddF(&sums[c], s);
    atomAddF(&sqs[c], s2);
}

template<int D>
__global__ __launch_bounds__(256) void k_bn_fin(const float* __restrict__ sums,
                                                const float* __restrict__ sqs,
                                                const float* __restrict__ g,
                                                const float* __restrict__ beta, int n,
                                                float* __restrict__ scale,
                                                float* __restrict__ shift) {
    int c = threadIdx.x;
    if (c < D) {
        float mu = sums[c] / (float)n;
        float var = sqs[c] / (float)n - mu * mu;
        float sc = g[c] * rsqrtf(var + EPS_BN);
        scale[c] = sc;
        shift[c] = beta[c] - mu * sc;
    }
}

template<int D>
__global__ __launch_bounds__(256) void k_bn_apply_h(const __half* __restrict__ X,
                                                    const float* __restrict__ scale,
                                                    const float* __restrict__ shift,
                                                    __half* __restrict__ H, int n) {
    int idx = blockIdx.x * 256 + threadIdx.x;   // 8-half chunks
    int total = n * (D / 8);
    if (idx >= total) return;
    int c = (idx % (D / 8)) * 8;
    uint4 d = ((const uint4*)X)[idx];
    const __half2* h = (const __half2*)&d;
    uint4 o; __half2* oh = (__half2*)&o;
#pragma unroll
    for (int j = 0; j < 4; ++j) {
        float2 f = __half22float2(h[j]);
        float y0 = fmaxf(0.f, f.x * scale[c + 2 * j] + shift[c + 2 * j]);
        float y1 = fmaxf(0.f, f.y * scale[c + 2 * j + 1] + shift[c + 2 * j + 1]);
        oh[j] = __floats2half2_rn(y0, y1);
    }
    ((uint4*)H)[idx] = o;
}

// ---------------- final linear ----------------
__global__ __launch_bounds__(256) void k_out(const __half* __restrict__ H,
                                             const float* __restrict__ Wout,
                                             const float* __restrict__ bout,
                                             float* __restrict__ out, int n) {
    __shared__ float Wl[128 * 10];
    __shared__ float bl[10];
    __shared__ float red[64 * 40];
    int tid = threadIdx.x;
    for (int i = tid; i < 1280; i += 256) Wl[i] = Wout[i];
    if (tid < 10) bl[tid] = bout[tid];
    __syncthreads();
    int rl = tid >> 2;
    int q = tid & 3;
    int r = blockIdx.x * 64 + rl;
    float p[10] = {};
    if (r < n) {
        const __half* a = H + (size_t)r * 128 + q * 32;
#pragma unroll 8
        for (int k = 0; k < 32; ++k) {
            float av = __half2float(a[k]);
            const float* wr = Wl + (q * 32 + k) * 10;
#pragma unroll
            for (int c = 0; c < 10; ++c) p[c] += av * wr[c];
        }
    }
    float* rr = red + (size_t)(rl * 4 + q) * 10;
#pragma unroll
    for (int c = 0; c < 10; ++c) rr[c] = p[c];
    __syncthreads();
    if (q == 0 && r < n) {
        const float* rb = red + (size_t)rl * 40;
#pragma unroll
        for (int c = 0; c < 10; ++c) {
            out[(size_t)r * 10 + c] = rb[c] + rb[10 + c] + rb[20 + c] + rb[30 + c] + bl[c];
        }
    }
}

// ---------------- launch ----------------
extern "C" void kernel_launch(void* const* d_in, const int* in_sizes, int n_in,
                              void* d_out, int out_size, void* d_ws, size_t ws_size,
                              hipStream_t stream) {
    const float* x    = (const float*)d_in[0];
    const int*   ei   = (const int*)d_in[1];
    const float* W1   = (const float*)d_in[2];
    const float* g1   = (const float*)d_in[4];
    const float* be1  = (const float*)d_in[5];
    const float* W2   = (const float*)d_in[6];
    const float* g2   = (const float*)d_in[8];
    const float* be2  = (const float*)d_in[9];
    const float* W3   = (const float*)d_in[10];
    const float* g3   = (const float*)d_in[12];
    const float* be3  = (const float*)d_in[13];
    const float* Wout = (const float*)d_in[14];
    const float* bout = (const float*)d_in[15];
    float* out = (float*)d_out;

    int n = in_sizes[0] / 128;
    int E = in_sizes[1] / 2;
    const int* esrc = ei;
    const int* edst = ei + E;
    int npad = cdiv(n, 128) * 128;
    int nb = cdiv(n, 1024);

    const size_t align = 256;
    auto al = [&](size_t s) { return (s + align - 1) & ~(align - 1); };
    size_t n4 = al((size_t)n * 4 + 512);      // slack past n for safety
    size_t E4 = al((size_t)E * 4);
    size_t szB = (size_t)npad * 256 * 2;      // f16 activation buffer

    char* ws = (char*)d_ws;
    size_t o_deg   = 0;
    size_t o_off   = o_deg + n4;
    size_t o_csr   = o_off + n4;
    size_t o_stats = o_csr + E4;
    size_t o_w1    = o_stats + 8192;
    size_t o_w2    = o_w1 + al(256 * 128 * 2);
    size_t o_w3    = o_w2 + al(256 * 256 * 2);
    size_t o_xh    = o_w3 + al(128 * 256 * 2);
    size_t o_BA    = o_xh + al((size_t)npad * 128 * 2);
    size_t o_BB    = o_BA + szB;
    size_t o_BC    = o_BB + szB;
    size_t need    = o_BC + szB;
    if (ws_size < need) return;

    int*    deg   = (int*)(ws + o_deg);
    float*  dinv  = (float*)(ws + o_deg);
    int*    off_  = (int*)(ws + o_off);
    int*    csr   = (int*)(ws + o_csr);
    float*  sums  = (float*)(ws + o_stats);
    float*  sqs   = (float*)(ws + o_stats + 1024);
    float*  scale = (float*)(ws + o_stats + 2048);
    float*  shift = (float*)(ws + o_stats + 3072);
    int*    bsum  = (int*)(ws + o_stats + 4096);
    __half* Wt1   = (__half*)(ws + o_w1);
    __half* Wt2   = (__half*)(ws + o_w2);
    __half* Wt3   = (__half*)(ws + o_w3);
    __half* xh    = (__half*)(ws + o_xh);
    __half* BA    = (__half*)(ws + o_BA);
    __half* BB    = (__half*)(ws + o_BB);
    __half* BC    = (__half*)(ws + o_BC);

    // ---- CSR build + dinv ----
    hipMemsetAsync(deg, 0, (size_t)n * 4, stream);
    k_deg<<<cdiv(E, 256), 256, 0, stream>>>(edst, E, deg);
    k_scan_reduce<<<nb, 256, 0, stream>>>(deg, n, bsum);
    k_scan_bsum<<<1, 64, 0, stream>>>(bsum, nb);
    k_scan_final<<<nb, 256, 0, stream>>>(deg, n, bsum, off_);
    k_dinv<<<cdiv(n, 256), 256, 0, stream>>>(deg, n);
    k_fill<<<cdiv(E, 256), 256, 0, stream>>>(esrc, edst, E, off_, csr);

    // ---- weights -> f16 transposed ----
    k_wt<128, 256><<<cdiv(128 * 256, 256), 256, 0, stream>>>(W1, Wt1);
    k_wt<256, 256><<<cdiv(256 * 256, 256), 256, 0, stream>>>(W2, Wt2);
    k_wt<256, 128><<<cdiv(256 * 128, 256), 256, 0, stream>>>(W3, Wt3);

    // ---- x -> f16, pre-scaled by dinv ----
    k_x2h<<<cdiv(n * 16, 256), 256, 0, stream>>>(x, dinv, xh, n);

    // ---- layer 1: S0 = gather(xh); P1 = S0@W1; BN+ReLU -> H1 (BA) ----
    k_gather_h<128><<<cdiv(n, 16), 256, 0, stream>>>(csr, off_, xh, dinv, BA, n);
    k_gemm_mfma<128, 256, false><<<dim3(npad / 128, 4), 256, 0, stream>>>(BA, Wt1, dinv, BB, n);
    hipMemsetAsync(sums, 0, 2048, stream);
    k_bn_stats_h<256><<<cdiv(n, 256), 256, 0, stream>>>(BB, n, sums, sqs);
    k_bn_fin<256><<<1, 256, 0, stream>>>(sums, sqs, g1, be1, n, scale, shift);
    k_bn_apply_h<256><<<cdiv(n * 32, 256), 256, 0, stream>>>(BB, scale, shift, BA, n);

    // ---- layer 2: P2' = (H1@W2)*dinv; S2 = gather(P2'); BN+ReLU -> H2 (BA) ----
    k_gemm_mfma<256, 256, true><<<dim3(npad / 128, 4), 256, 0, stream>>>(BA, Wt2, dinv, BB, n);
    k_gather_h<256><<<cdiv(n, 8), 256, 0, stream>>>(csr, off_, BB, dinv, BC, n);
    hipMemsetAsync(sums, 0, 2048, stream);
    k_bn_stats_h<256><<<cdiv(n, 256), 256, 0, stream>>>(BC, n, sums, sqs);
    k_bn_fin<256><<<1, 256, 0, stream>>>(sums, sqs, g2, be2, n, scale, shift);
    k_bn_apply_h<256><<<cdiv(n * 32, 256), 256, 0, stream>>>(BC, scale, shift, BA, n);

    // ---- layer 3: P3' = (H2@W3)*dinv; S3 = gather(P3'); BN+ReLU -> H3 (BA) ----
    k_gemm_mfma<256, 128, true><<<dim3(npad / 128, 2), 256, 0, stream>>>(BA, Wt3, dinv, BB, n);
    k_gather_h<128><<<cdiv(n, 16), 256, 0, stream>>>(csr, off_, BB, dinv, BC, n);
    hipMemsetAsync(sums, 0, 2048, stream);
    k_bn_stats_h<128><<<cdiv(n, 256), 256, 0, stream>>>(BC, n, sums, sqs);
    k_bn_fin<128><<<1, 128, 0, stream>>>(sums, sqs, g3, be3, n, scale, shift);
    k_bn_apply_h<128><<<cdiv(n * 16, 256), 256, 0, stream>>>(BC, scale, shift, BA, n);

    // ---- output layer ----
    k_out<<<cdiv(n, 64), 256, 0, stream>>>(BA, Wout, bout, out, n);
}

// Round 4
// 784.248 us; speedup vs baseline: 14.7897x; 1.2337x over previous
//
#include <hip/hip_runtime.h>
#include <hip/hip_fp16.h>
#include <cstdint>
#include <cstddef>

#define EPS_BN 1e-5f

static inline int cdiv(int a, int b) { return (a + b - 1) / b; }

using half8   = __attribute__((ext_vector_type(8))) _Float16;
using floatx4 = __attribute__((ext_vector_type(4))) float;

__device__ __forceinline__ float atomAddF(float* p, float v) {
    return unsafeAtomicAdd(p, v);   // HW global_atomic_add_f32 on gfx950
}

// ================= bucketed CSR build =================
// bucket = dst >> 9 (512 nodes per bucket); NBUCK <= 256 required.

// Pass A: per-block histogram over buckets; H layout bucket-major: H[b*NBLK + blk]
__global__ __launch_bounds__(256) void k_hist(const int* __restrict__ dst, int E,
                                              int NBLK, int NBUCK, int* __restrict__ H) {
    __shared__ int h[256];
    int t = threadIdx.x;
    h[t] = 0;
    __syncthreads();
    int base = blockIdx.x * 4096;
#pragma unroll
    for (int j = 0; j < 16; ++j) {
        int e = base + j * 256 + t;
        if (e < E) atomicAdd(&h[dst[e] >> 9], 1);
    }
    __syncthreads();
    if (t < NBUCK) H[t * NBLK + blockIdx.x] = h[t];
}

// generic exclusive scan (3 kernels), 1024 elems/block
__global__ __launch_bounds__(256) void k_scan_reduce(const int* __restrict__ in, int m,
                                                     int* __restrict__ bsum) {
    int base = blockIdx.x * 1024;
    int t = threadIdx.x;
    int s = 0;
#pragma unroll
    for (int i = 0; i < 4; ++i) {
        int idx = base + t * 4 + i;
        if (idx < m) s += in[idx];
    }
    __shared__ int sm[256];
    sm[t] = s;
    __syncthreads();
    for (int off = 128; off > 0; off >>= 1) {
        if (t < off) sm[t] += sm[t + off];
        __syncthreads();
    }
    if (t == 0) bsum[blockIdx.x] = sm[0];
}

__global__ void k_scan_bsum(int* __restrict__ bsum, int nb) {
    if (threadIdx.x == 0 && blockIdx.x == 0) {
        int acc = 0;
        for (int i = 0; i < nb; ++i) { int v = bsum[i]; bsum[i] = acc; acc += v; }
    }
}

__global__ __launch_bounds__(256) void k_scan_final(const int* __restrict__ in, int m,
                                                    const int* __restrict__ bsum,
                                                    int* __restrict__ outS) {
    int base = blockIdx.x * 1024;
    int t = threadIdx.x;
    int v[4];
    int s = 0;
#pragma unroll
    for (int i = 0; i < 4; ++i) {
        int idx = base + t * 4 + i;
        v[i] = (idx < m) ? in[idx] : 0;
        s += v[i];
    }
    __shared__ int sm[256];
    sm[t] = s;
    __syncthreads();
    for (int off = 1; off < 256; off <<= 1) {
        int x = (t >= off) ? sm[t - off] : 0;
        __syncthreads();
        sm[t] += x;
        __syncthreads();
    }
    int excl = sm[t] - s + bsum[blockIdx.x];
#pragma unroll
    for (int i = 0; i < 4; ++i) {
        int idx = base + t * 4 + i;
        if (idx < m) { outS[idx] = excl; excl += v[i]; }
    }
}

// Pass B: scatter edges into bucket-sorted pairs[] via per-block LDS cursors
__global__ __launch_bounds__(256) void k_bucket(const int* __restrict__ src,
                                                const int* __restrict__ dst, int E,
                                                int NBLK, int NBUCK,
                                                const int* __restrict__ S,
                                                int2* __restrict__ pairs) {
    __shared__ int cur[256];
    int t = threadIdx.x;
    if (t < NBUCK) cur[t] = S[t * NBLK + blockIdx.x];
    __syncthreads();
    int base = blockIdx.x * 4096;
#pragma unroll
    for (int j = 0; j < 16; ++j) {
        int e = base + j * 256 + t;
        if (e < E) {
            int s = src[e], d = dst[e];
            int p = atomicAdd(&cur[d >> 9], 1);
            pairs[p] = make_int2(s, d);
        }
    }
}

// Pass C: per-bucket deg count + node scan + dinv + fine fill, all LDS-local
__global__ __launch_bounds__(256) void k_build(const int2* __restrict__ pairs,
                                               const int* __restrict__ S,
                                               int NBLK, int NBUCK, int n, int E,
                                               int* __restrict__ endoff,
                                               float* __restrict__ dinv,
                                               int* __restrict__ csr) {
    int b = blockIdx.x;
    int nbase = b << 9;
    int bstart = S[b * NBLK];
    int bend = (b == NBUCK - 1) ? E : S[(b + 1) * NBLK];
    int t = threadIdx.x;
    __shared__ int sdeg[512];
    __shared__ int scur[512];
    __shared__ int stmp[256];
    sdeg[t] = 0; sdeg[t + 256] = 0;
    __syncthreads();
    for (int e = bstart + t; e < bend; e += 256)
        atomicAdd(&sdeg[pairs[e].y - nbase], 1);
    __syncthreads();
    int d0 = sdeg[2 * t], d1 = sdeg[2 * t + 1];
    int ps = d0 + d1;
    stmp[t] = ps;
    __syncthreads();
    for (int off = 1; off < 256; off <<= 1) {
        int x = (t >= off) ? stmp[t - off] : 0;
        __syncthreads();
        stmp[t] += x;
        __syncthreads();
    }
    int c0 = bstart + stmp[t] - ps;     // start of node 2t
    int c1 = c0 + d0;                    // start of node 2t+1 == end of node 2t
    scur[2 * t] = c0;
    scur[2 * t + 1] = c1;
    int v0 = nbase + 2 * t, v1 = v0 + 1;
    if (v0 < n) { endoff[v0] = c1;      dinv[v0] = rsqrtf((float)(d0 + 1)); }
    if (v1 < n) { endoff[v1] = c1 + d1; dinv[v1] = rsqrtf((float)(d1 + 1)); }
    __syncthreads();
    for (int e = bstart + t; e < bend; e += 256) {
        int2 p = pairs[e];
        int pos = atomicAdd(&scur[p.y - nbase], 1);
        csr[pos] = p.x;
    }
}

// ================= weights / input conversion =================
template<int K, int NC>
__global__ __launch_bounds__(256) void k_wt(const float* __restrict__ W,
                                            __half* __restrict__ Wt) {
    int idx = blockIdx.x * 256 + threadIdx.x;
    if (idx >= K * NC) return;
    int k = idx / NC, c = idx % NC;
    Wt[(size_t)c * K + k] = __float2half(W[idx]);
}

__global__ __launch_bounds__(256) void k_x2h(const float* __restrict__ x,
                                             const float* __restrict__ dinv,
                                             __half* __restrict__ xh, int n) {
    int idx = blockIdx.x * 256 + threadIdx.x;   // 8-half chunks, D=128
    int total = n * 16;
    if (idx >= total) return;
    int row = idx >> 4;
    float dv = dinv[row];
    const float4* p = (const float4*)x + (size_t)idx * 2;
    float4 a = p[0], b = p[1];
    uint4 o; __half2* oh = (__half2*)&o;
    oh[0] = __floats2half2_rn(a.x * dv, a.y * dv);
    oh[1] = __floats2half2_rn(a.z * dv, a.w * dv);
    oh[2] = __floats2half2_rn(b.x * dv, b.y * dv);
    oh[3] = __floats2half2_rn(b.z * dv, b.w * dv);
    ((uint4*)xh)[idx] = o;
}

// ================= CSR gather (rows pre-scaled by dinv[src]) =================
template<int D>
__global__ __launch_bounds__(256) void k_gather_h(const int* __restrict__ csr,
                                                  const int* __restrict__ endoff,
                                                  const __half* __restrict__ P,
                                                  const float* __restrict__ dinv,
                                                  __half* __restrict__ S, int n) {
    constexpr int LPN = D / 8;
    constexpr int NPB = 256 / LPN;
    int v = blockIdx.x * NPB + threadIdx.x / LPN;
    if (v >= n) return;
    int lane = threadIdx.x % LPN;
    int beg = (v == 0) ? 0 : endoff[v - 1];
    int end = endoff[v];
    float dv = dinv[v];
    float acc[8];
    {
        uint4 d = *((const uint4*)(P + (size_t)v * D) + lane);   // self term
        const __half2* h = (const __half2*)&d;
#pragma unroll
        for (int j = 0; j < 4; ++j) {
            float2 f = __half22float2(h[j]);
            acc[2 * j] = f.x; acc[2 * j + 1] = f.y;
        }
    }
    int i = beg;
    for (; i + 3 < end; i += 4) {
        int s0 = csr[i], s1 = csr[i + 1], s2 = csr[i + 2], s3 = csr[i + 3];
        uint4 d0 = *((const uint4*)(P + (size_t)s0 * D) + lane);
        uint4 d1 = *((const uint4*)(P + (size_t)s1 * D) + lane);
        uint4 d2 = *((const uint4*)(P + (size_t)s2 * D) + lane);
        uint4 d3 = *((const uint4*)(P + (size_t)s3 * D) + lane);
        const __half2* h0 = (const __half2*)&d0;
        const __half2* h1 = (const __half2*)&d1;
        const __half2* h2 = (const __half2*)&d2;
        const __half2* h3 = (const __half2*)&d3;
#pragma unroll
        for (int j = 0; j < 4; ++j) {
            float2 f0 = __half22float2(h0[j]);
            float2 f1 = __half22float2(h1[j]);
            float2 f2 = __half22float2(h2[j]);
            float2 f3 = __half22float2(h3[j]);
            acc[2 * j]     += (f0.x + f1.x) + (f2.x + f3.x);
            acc[2 * j + 1] += (f0.y + f1.y) + (f2.y + f3.y);
        }
    }
    for (; i < end; ++i) {
        int s0 = csr[i];
        uint4 d0 = *((const uint4*)(P + (size_t)s0 * D) + lane);
        const __half2* h0 = (const __half2*)&d0;
#pragma unroll
        for (int j = 0; j < 4; ++j) {
            float2 f0 = __half22float2(h0[j]);
            acc[2 * j] += f0.x; acc[2 * j + 1] += f0.y;
        }
    }
    uint4 o; __half2* oh = (__half2*)&o;
#pragma unroll
    for (int j = 0; j < 4; ++j)
        oh[j] = __floats2half2_rn(acc[2 * j] * dv, acc[2 * j + 1] * dv);
    *((uint4*)(S + (size_t)v * D) + lane) = o;
}

// ================= MFMA GEMM with optional fused input-BN+ReLU and output dinv scale
template<int K, int NC, bool SCALE, bool BNIN>
__global__ __launch_bounds__(256) void k_gemm_mfma(const __half* __restrict__ A,
                                                   const __half* __restrict__ Wt,
                                                   const float* __restrict__ dinv,
                                                   const float* __restrict__ bnsc,
                                                   const float* __restrict__ bnsh,
                                                   __half* __restrict__ C, int n) {
    constexpr int LDA = 40;
    __shared__ _Float16 As[128 * LDA];
    __shared__ _Float16 Bs[64 * LDA];
    __shared__ float ssc[K];
    __shared__ float ssh[K];
    int tid = threadIdx.x;
    if (BNIN) {
        for (int i = tid; i < K; i += 256) { ssc[i] = bnsc[i]; ssh[i] = bnsh[i]; }
        __syncthreads();
    }
    int wave = tid >> 6, lane = tid & 63;
    int q = lane >> 4, l16 = lane & 15;
    int row0 = blockIdx.x * 128;
    int col0 = blockIdx.y * 64;
    floatx4 acc[2][4];
#pragma unroll
    for (int r = 0; r < 2; ++r)
#pragma unroll
        for (int c = 0; c < 4; ++c) acc[r][c] = (floatx4)0.0f;

    for (int k0 = 0; k0 < K; k0 += 32) {
#pragma unroll
        for (int i = 0; i < 2; ++i) {       // A tile 128 x 32
            int s = tid + i * 256;
            int r = s >> 2, ks = s & 3;
            uint4 d = *(const uint4*)(A + (size_t)(row0 + r) * K + k0 + ks * 8);
            if (BNIN) {
                const __half2* h = (const __half2*)&d;
                uint4 o; __half2* oh = (__half2*)&o;
                int kb = k0 + ks * 8;
#pragma unroll
                for (int j = 0; j < 4; ++j) {
                    float2 f = __half22float2(h[j]);
                    float y0 = fmaxf(0.f, f.x * ssc[kb + 2 * j]     + ssh[kb + 2 * j]);
                    float y1 = fmaxf(0.f, f.y * ssc[kb + 2 * j + 1] + ssh[kb + 2 * j + 1]);
                    oh[j] = __floats2half2_rn(y0, y1);
                }
                d = o;
            }
            *(uint4*)&As[r * LDA + ks * 8] = d;
        }
        {                                    // B tile 64 x 32
            int r = tid >> 2, ks = tid & 3;
            uint4 d = *(const uint4*)(Wt + (size_t)(col0 + r) * K + k0 + ks * 8);
            *(uint4*)&Bs[r * LDA + ks * 8] = d;
        }
        __syncthreads();
        half8 bf[4];
#pragma unroll
        for (int c = 0; c < 4; ++c)
            bf[c] = *(const half8*)&Bs[(c * 16 + l16) * LDA + q * 8];
#pragma unroll
        for (int r = 0; r < 2; ++r) {
            half8 af = *(const half8*)&As[(wave * 32 + r * 16 + l16) * LDA + q * 8];
#pragma unroll
            for (int c = 0; c < 4; ++c)
                acc[r][c] = __builtin_amdgcn_mfma_f32_16x16x32_f16(af, bf[c], acc[r][c], 0, 0, 0);
        }
        __syncthreads();
    }
#pragma unroll
    for (int r = 0; r < 2; ++r) {
#pragma unroll
        for (int reg = 0; reg < 4; ++reg) {
            int grow = row0 + wave * 32 + r * 16 + q * 4 + reg;
            float sc = 1.f;
            if (SCALE) sc = (grow < n) ? dinv[grow] : 0.f;
            __half* cp = C + (size_t)grow * NC + col0 + l16;
#pragma unroll
            for (int c = 0; c < 4; ++c)
                cp[c * 16] = __float2half(acc[r][c][reg] * sc);
        }
    }
}

// ================= BatchNorm stats =================
template<int D>
__global__ __launch_bounds__(256) void k_bn_stats_h(const __half* __restrict__ X, int n,
                                                    float* __restrict__ sums,
                                                    float* __restrict__ sqs) {
    constexpr int SUB = 256 / D;
    int c = threadIdx.x % D;
    int sub = threadIdx.x / D;
    int base = blockIdx.x * 256;
    float s = 0.f, s2 = 0.f;
    for (int i = sub; i < 256; i += SUB) {
        int r = base + i;
        if (r < n) {
            float v = __half2float(X[(size_t)r * D + c]);
            s += v; s2 += v * v;
        }
    }
    atomAddF(&sums[c], s);
    atomAddF(&sqs[c], s2);
}

template<int D>
__global__ __launch_bounds__(256) void k_bn_fin(const float* __restrict__ sums,
                                                const float* __restrict__ sqs,
                                                const float* __restrict__ g,
                                                const float* __restrict__ beta, int n,
                                                float* __restrict__ scale,
                                                float* __restrict__ shift) {
    int c = threadIdx.x;
    if (c < D) {
        float mu = sums[c] / (float)n;
        float var = sqs[c] / (float)n - mu * mu;
        float sc = g[c] * rsqrtf(var + EPS_BN);
        scale[c] = sc;
        shift[c] = beta[c] - mu * sc;
    }
}

// ================= final linear with fused BN+ReLU on input =================
__global__ __launch_bounds__(256) void k_out(const __half* __restrict__ H,
                                             const float* __restrict__ bnsc,
                                             const float* __restrict__ bnsh,
                                             const float* __restrict__ Wout,
                                             const float* __restrict__ bout,
                                             float* __restrict__ out, int n) {
    __shared__ float Wl[128 * 10];
    __shared__ float bl[10];
    __shared__ float osc[128];
    __shared__ float osh[128];
    __shared__ float red[64 * 40];
    int tid = threadIdx.x;
    for (int i = tid; i < 1280; i += 256) Wl[i] = Wout[i];
    if (tid < 10) bl[tid] = bout[tid];
    if (tid < 128) { osc[tid] = bnsc[tid]; osh[tid] = bnsh[tid]; }
    __syncthreads();
    int rl = tid >> 2;
    int q = tid & 3;
    int r = blockIdx.x * 64 + rl;
    float p[10] = {};
    if (r < n) {
        const __half* a = H + (size_t)r * 128 + q * 32;
#pragma unroll 8
        for (int k = 0; k < 32; ++k) {
            int col = q * 32 + k;
            float av = fmaxf(0.f, __half2float(a[k]) * osc[col] + osh[col]);
            const float* wr = Wl + col * 10;
#pragma unroll
            for (int c = 0; c < 10; ++c) p[c] += av * wr[c];
        }
    }
    float* rr = red + (size_t)(rl * 4 + q) * 10;
#pragma unroll
    for (int c = 0; c < 10; ++c) rr[c] = p[c];
    __syncthreads();
    if (q == 0 && r < n) {
        const float* rb = red + (size_t)rl * 40;
#pragma unroll
        for (int c = 0; c < 10; ++c) {
            out[(size_t)r * 10 + c] = rb[c] + rb[10 + c] + rb[20 + c] + rb[30 + c] + bl[c];
        }
    }
}

// ================= launch =================
extern "C" void kernel_launch(void* const* d_in, const int* in_sizes, int n_in,
                              void* d_out, int out_size, void* d_ws, size_t ws_size,
                              hipStream_t stream) {
    const float* x    = (const float*)d_in[0];
    const int*   ei   = (const int*)d_in[1];
    const float* W1   = (const float*)d_in[2];
    const float* g1   = (const float*)d_in[4];
    const float* be1  = (const float*)d_in[5];
    const float* W2   = (const float*)d_in[6];
    const float* g2   = (const float*)d_in[8];
    const float* be2  = (const float*)d_in[9];
    const float* W3   = (const float*)d_in[10];
    const float* g3   = (const float*)d_in[12];
    const float* be3  = (const float*)d_in[13];
    const float* Wout = (const float*)d_in[14];
    const float* bout = (const float*)d_in[15];
    float* out = (float*)d_out;

    int n = in_sizes[0] / 128;
    int E = in_sizes[1] / 2;
    const int* esrc = ei;
    const int* edst = ei + E;
    int npad = cdiv(n, 128) * 128;
    int NBLK = cdiv(E, 4096);
    int NBUCK = (n + 511) >> 9;
    if (NBUCK > 256) return;            // bucket scheme requires n <= 131072
    int m = NBUCK * NBLK;
    int nb2 = cdiv(m, 1024);

    const size_t align = 256;
    auto al = [&](size_t s) { return (s + align - 1) & ~(align - 1); };
    size_t n4 = al((size_t)n * 4 + 512);

    char* ws = (char*)d_ws;
    size_t o_end   = 0;                       // endoff (n ints)
    size_t o_dinv  = o_end + n4;              // dinv (n floats)
    size_t o_stats = o_dinv + n4;             // sums/sqs/scale/shift + bsum
    size_t o_H     = o_stats + 8192;          // raw hist (m ints)
    size_t o_Hs    = o_H + al((size_t)m * 4); // scanned hist (m ints)
    size_t o_csr   = o_Hs + al((size_t)m * 4);
    size_t o_pairs = o_csr + al((size_t)E * 4);
    size_t o_w1    = o_pairs + al((size_t)E * 8);
    size_t o_w2    = o_w1 + al(256 * 128 * 2);
    size_t o_w3    = o_w2 + al(256 * 256 * 2);
    size_t o_A128a = o_w3 + al(128 * 256 * 2);          // xh / S3
    size_t o_A128b = o_A128a + al((size_t)npad * 128 * 2); // G1 / P3
    size_t o_A256a = o_A128b + al((size_t)npad * 128 * 2); // P1 / S2
    size_t o_A256b = o_A256a + al((size_t)npad * 256 * 2); // P2
    size_t need    = o_A256b + (size_t)npad * 256 * 2;
    if (ws_size < need) return;

    int*    endoff = (int*)(ws + o_end);
    float*  dinv   = (float*)(ws + o_dinv);
    float*  sums   = (float*)(ws + o_stats);
    float*  sqs    = (float*)(ws + o_stats + 1024);
    float*  scale  = (float*)(ws + o_stats + 2048);
    float*  shift  = (float*)(ws + o_stats + 3072);
    int*    bsum   = (int*)(ws + o_stats + 4096);
    int*    H      = (int*)(ws + o_H);
    int*    Hs     = (int*)(ws + o_Hs);
    int*    csr    = (int*)(ws + o_csr);
    int2*   pairs  = (int2*)(ws + o_pairs);
    __half* Wt1    = (__half*)(ws + o_w1);
    __half* Wt2    = (__half*)(ws + o_w2);
    __half* Wt3    = (__half*)(ws + o_w3);
    __half* xh     = (__half*)(ws + o_A128a);
    __half* S3     = (__half*)(ws + o_A128a);
    __half* G1     = (__half*)(ws + o_A128b);
    __half* P3     = (__half*)(ws + o_A128b);
    __half* P1     = (__half*)(ws + o_A256a);
    __half* S2     = (__half*)(ws + o_A256a);
    __half* P2     = (__half*)(ws + o_A256b);

    // ---- bucketed CSR build ----
    k_hist<<<NBLK, 256, 0, stream>>>(edst, E, NBLK, NBUCK, H);
    k_scan_reduce<<<nb2, 256, 0, stream>>>(H, m, bsum);
    k_scan_bsum<<<1, 64, 0, stream>>>(bsum, nb2);
    k_scan_final<<<nb2, 256, 0, stream>>>(H, m, bsum, Hs);
    k_bucket<<<NBLK, 256, 0, stream>>>(esrc, edst, E, NBLK, NBUCK, Hs, pairs);
    k_build<<<NBUCK, 256, 0, stream>>>(pairs, Hs, NBLK, NBUCK, n, E, endoff, dinv, csr);

    // ---- weights -> f16 transposed ----
    k_wt<128, 256><<<cdiv(128 * 256, 256), 256, 0, stream>>>(W1, Wt1);
    k_wt<256, 256><<<cdiv(256 * 256, 256), 256, 0, stream>>>(W2, Wt2);
    k_wt<256, 128><<<cdiv(256 * 128, 256), 256, 0, stream>>>(W3, Wt3);

    // ---- x -> f16 pre-scaled by dinv ----
    k_x2h<<<cdiv(n * 16, 256), 256, 0, stream>>>(x, dinv, xh, n);

    // ---- layer 1: G1 = gather(xh); P1 = G1@W1; stats ----
    k_gather_h<128><<<cdiv(n, 16), 256, 0, stream>>>(csr, endoff, xh, dinv, G1, n);
    k_gemm_mfma<128, 256, false, false><<<dim3(npad / 128, 4), 256, 0, stream>>>(
        G1, Wt1, dinv, nullptr, nullptr, P1, n);
    hipMemsetAsync(sums, 0, 2048, stream);
    k_bn_stats_h<256><<<cdiv(n, 256), 256, 0, stream>>>(P1, n, sums, sqs);
    k_bn_fin<256><<<1, 256, 0, stream>>>(sums, sqs, g1, be1, n, scale, shift);

    // ---- layer 2: P2 = (BN1(P1)@W2)*dinv; S2 = gather(P2); stats ----
    k_gemm_mfma<256, 256, true, true><<<dim3(npad / 128, 4), 256, 0, stream>>>(
        P1, Wt2, dinv, scale, shift, P2, n);
    k_gather_h<256><<<cdiv(n, 8), 256, 0, stream>>>(csr, endoff, P2, dinv, S2, n);
    hipMemsetAsync(sums, 0, 2048, stream);
    k_bn_stats_h<256><<<cdiv(n, 256), 256, 0, stream>>>(S2, n, sums, sqs);
    k_bn_fin<256><<<1, 256, 0, stream>>>(sums, sqs, g2, be2, n, scale, shift);

    // ---- layer 3: P3 = (BN2(S2)@W3)*dinv; S3 = gather(P3); stats ----
    k_gemm_mfma<256, 128, true, true><<<dim3(npad / 128, 2), 256, 0, stream>>>(
        S2, Wt3, dinv, scale, shift, P3, n);
    k_gather_h<128><<<cdiv(n, 16), 256, 0, stream>>>(csr, endoff, P3, dinv, S3, n);
    hipMemsetAsync(sums, 0, 2048, stream);
    k_bn_stats_h<128><<<cdiv(n, 256), 256, 0, stream>>>(S3, n, sums, sqs);
    k_bn_fin<128><<<1, 128, 0, stream>>>(sums, sqs, g3, be3, n, scale, shift);

    // ---- output: out = ReLU(BN3(S3)) @ Wout + bout ----
    k_out<<<cdiv(n, 64), 256, 0, stream>>>(S3, scale, shift, Wout, bout, out, n);
}